// Round 2
// baseline (469.245 us; speedup 1.0000x reference)
//
#include <hip/hip_runtime.h>

#define HWD 224
#define HP 56
#define WPD 56
#define EDIM 128
#define NCLS 20
#define BSZ 64
#define NPATCH (BSZ*HP*WPD)      // 200704
#define NOUT (NPATCH*EDIM)       // 25690112
#define PPB 49                   // patches per block
#define NBLK (NPATCH/PPB)        // 4096 exactly

// One wave per block. Lane owns channels e0=2*lane, e0+1 (weights persistent in
// VGPRs, amortized over 49 patches). Patch inputs are wave-uniform -> scalar
// loads; FMA dominates VALU. LN via shfl_xor; histogram lane==class vs uniform
// mask; argmax butterfly keeps first-max (jnp.argmax) tie-break.
__global__ __launch_bounds__(64) void fused_patch_embed(
    const float* __restrict__ rgb, const int* __restrict__ mask,
    const float* __restrict__ wgt, const float* __restrict__ pb,
    const float* __restrict__ gam, const float* __restrict__ bet,
    const float* __restrict__ sem, const float* __restrict__ cw,
    float* __restrict__ out, int out_size)
{
    const int lane = (int)threadIdx.x;       // 0..63
    const int e0 = 2 * lane;

    // --- persistent weights: 2 rows x 64 = 32 float4 regs ---
    float4 w0[16], w1[16];
#pragma unroll
    for (int j = 0; j < 16; ++j) {
        w0[j] = *(const float4*)(wgt + (size_t)e0 * 64 + 4 * j);
        w1[j] = *(const float4*)(wgt + (size_t)(e0 + 1) * 64 + 4 * j);
    }
    const float2 g2  = *(const float2*)(gam + e0);
    const float2 b2  = *(const float2*)(bet + e0);
    const float2 pbv = *(const float2*)(pb  + e0);
    const float mycw = (lane < NCLS) ? cw[lane] : 0.0f;

    const int pbase = (int)blockIdx.x * PPB;
    for (int pi = 0; pi < PPB; ++pi) {
        const int p  = pbase + pi;
        const int wp = p % WPD;
        const int tq = p / WPD;
        const int hp = tq % HP;
        const int b  = tq / HP;
        const int r0 = hp * 4, c0 = wp * 4;

        float a0 = pbv.x, a1 = pbv.y;

        // --- rgb channels (k = ch*16 + kh*4 + kw) ---
#pragma unroll
        for (int ch = 0; ch < 3; ++ch) {
#pragma unroll
            for (int kh = 0; kh < 4; ++kh) {
                const float4 xv = *(const float4*)(rgb + ((size_t)(b * 3 + ch) * HWD + (size_t)(r0 + kh)) * HWD + c0);
                const float4 wa = w0[ch * 4 + kh], wb = w1[ch * 4 + kh];
                a0 += wa.x * xv.x + wa.y * xv.y + wa.z * xv.z + wa.w * xv.w;
                a1 += wb.x * xv.x + wb.y * xv.y + wb.z * xv.z + wb.w * xv.w;
            }
        }
        // --- mask channel (i=3), keep ints for histogram ---
        int4 mr[4];
#pragma unroll
        for (int kh = 0; kh < 4; ++kh) {
            mr[kh] = *(const int4*)(mask + ((size_t)b * HWD + (size_t)(r0 + kh)) * HWD + c0);
            const float4 xv = make_float4((float)mr[kh].x, (float)mr[kh].y,
                                          (float)mr[kh].z, (float)mr[kh].w);
            const float4 wa = w0[12 + kh], wb = w1[12 + kh];
            a0 += wa.x * xv.x + wa.y * xv.y + wa.z * xv.z + wa.w * xv.w;
            a1 += wb.x * xv.x + wb.y * xv.y + wb.z * xv.z + wb.w * xv.w;
        }

        // --- LayerNorm over 128 channels (2 per lane) ---
        float s = a0 + a1, sq = a0 * a0 + a1 * a1;
#pragma unroll
        for (int m = 32; m >= 1; m >>= 1) {
            s  += __shfl_xor(s,  m, 64);
            sq += __shfl_xor(sq, m, 64);
        }
        const float mu   = s * (1.0f / EDIM);
        const float rstd = rsqrtf(sq * (1.0f / EDIM) - mu * mu + 1e-5f);

        // --- weighted class histogram + argmax (first-max tie-break) ---
        int cnt = 0;
#pragma unroll
        for (int kh = 0; kh < 4; ++kh) {
            cnt += (mr[kh].x == lane) + (mr[kh].y == lane) +
                   (mr[kh].z == lane) + (mr[kh].w == lane);
        }
        float score = (lane < NCLS) ? (float)cnt * mycw : -1.0f;
        int best = lane;
#pragma unroll
        for (int m = 1; m < 64; m <<= 1) {
            const float so = __shfl_xor(score, m, 64);
            const int   io = __shfl_xor(best,  m, 64);
            if (so > score || (so == score && io < best)) { score = so; best = io; }
        }

        // --- sem add + store ---
        const float2 sv = *(const float2*)(sem + (size_t)best * EDIM + e0);
        const float y0 = (a0 - mu) * rstd * g2.x + b2.x + sv.x;
        const float y1 = (a1 - mu) * rstd * g2.y + b2.y + sv.y;
        *(float2*)(out + (size_t)p * EDIM + e0) = make_float2(y0, y1);
    }

    // tuple second output (Hp, Wp) = (56, 56) if the harness appended it
    if (blockIdx.x == 0 && lane == 0) {
        for (int i = NOUT; i < out_size; ++i) out[i] = 56.0f;
    }
}

extern "C" void kernel_launch(void* const* d_in, const int* in_sizes, int n_in,
                              void* d_out, int out_size, void* d_ws, size_t ws_size,
                              hipStream_t stream) {
    const float* rgb  = (const float*)d_in[0];
    const int*   mask = (const int*)d_in[1];
    const float* wgt  = (const float*)d_in[2];
    const float* pb   = (const float*)d_in[3];
    const float* gam  = (const float*)d_in[4];
    const float* bet  = (const float*)d_in[5];
    const float* sem  = (const float*)d_in[6];
    const float* cw   = (const float*)d_in[7];
    float* out = (float*)d_out;

    fused_patch_embed<<<NBLK, 64, 0, stream>>>(rgb, mask, wgt, pb, gam, bet,
                                               sem, cw, out, out_size);
}